// Round 1
// baseline (126.429 us; speedup 1.0000x reference)
//
#include <hip/hip_runtime.h>

#define N_TOTAL 32768
#define D_DIM   512
#define C_DIM   64
#define K_DIM   16
#define M_DIM   128
#define NODES_  15
#define ROWS    16

typedef unsigned short u16;
typedef unsigned int   u32;

__device__ __forceinline__ u32 f2bf_bits(float f) {
    u32 u = __float_as_uint(f);
    return (u + 0x7FFFu + ((u >> 16) & 1u)) >> 16;   // RNE
}
__device__ __forceinline__ float bf_lo(u32 u) { return __uint_as_float(u << 16); }
__device__ __forceinline__ float bf_hi(u32 u) { return __uint_as_float(u & 0xFFFF0000u); }

// ---------------------------------------------------------------------------
// Kernel 1: pair-merged LUT. LUT2[p][kk][m] (bf16), p=0..31, kk=k0|(k1<<4):
//   LUT2 = L[m][(2p)*16+k0] + L[m][(2p+1)*16+k1]
// 32*256*128 bf16 = 2 MB (L2/L3-resident). ~1-2 us, not the bottleneck.
// ---------------------------------------------------------------------------
__global__ __launch_bounds__(256) void build_lut_kernel(
    const float* __restrict__ L, u16* __restrict__ LUT)
{
    int idx = blockIdx.x * 256 + threadIdx.x;   // 131072 threads
    int q  = idx & 15;                          // col-group (8 cols)
    int kk = (idx >> 4) & 255;
    int p  = idx >> 12;                         // 0..31
    int c0 = (2 * p) * 16 + (kk & 15);
    int c1 = (2 * p + 1) * 16 + (kk >> 4);
    u32 w[4];
    #pragma unroll
    for (int h = 0; h < 4; ++h) {
        int m0 = q * 8 + 2 * h;
        float a0 = L[m0 * 1024 + c0]       + L[m0 * 1024 + c1];
        float a1 = L[(m0 + 1) * 1024 + c0] + L[(m0 + 1) * 1024 + c1];
        w[h] = f2bf_bits(a0) | (f2bf_bits(a1) << 16);
    }
    *(uint4*)(LUT + (size_t)((p << 8) | kk) * M_DIM + q * 8) =
        make_uint4(w[0], w[1], w[2], w[3]);
}

// ---------------------------------------------------------------------------
// Kernel 2 (fused, wave-autonomous): wave w of each block owns rows
// blockIdx.x*16 + w*4 .. +3. Phase 1 computes the 4-bit tree codes for those
// 4 rows (lane = class, codes packed 4x4b into one u32 per lane, all gathers
// issued before the T-staging barrier). Phase 2 consumes ONLY this wave's
// codes via v_readlane broadcasts -> no sCode LDS, no inter-phase
// __syncthreads; waves pipeline HBM phase against L2 phase freely.
// Forward of the STE reference: sign(h) drives a binary descent; argmax leaf
// == descent leaf. h==0 -> bit 0 == argmax first-max tie rule.
// ---------------------------------------------------------------------------
__global__ __launch_bounds__(256) void fused_kernel(
    const float* __restrict__ I,
    const float* __restrict__ T,
    const int* __restrict__ dims,
    const u16* __restrict__ LUT,
    float* __restrict__ out)
{
    __shared__ float sT[C_DIM * NODES_];    // 3.75 KB

    const int tid  = threadIdx.x;
    const int lane = tid & 63;              // class c in phase 1
    const int wv   = tid >> 6;              // wave 0..3
    const int rowBase = blockIdx.x * ROWS + wv * 4;

    // per-lane dim indices: one coalesced int4 from global (1 KB, L2-hot)
    const int4 dml = ((const int4*)dims)[lane];

    // issue all 16 I-gathers first (addresses independent of tree path);
    // each load inst: 64 lanes hit ~16 lines of one 2 KB row (dims sorted)
    float vv[4][4];
    #pragma unroll
    for (int rr = 0; rr < 4; ++rr) {
        const float* v = I + (size_t)(rowBase + rr) * D_DIM;
        vv[rr][0] = v[dml.x];
        vv[rr][1] = v[dml.y];
        vv[rr][2] = v[dml.z];
        vv[rr][3] = v[dml.w];
    }

    // stage thresholds while the gathers are in flight
    for (int j = tid; j < C_DIM * NODES_; j += 256) sT[j] = T[j];
    __syncthreads();   // only barrier in the kernel; hidden under HBM latency

    // ---- phase 1: depth-4 descent, 4 rows, codes packed into one u32 ----
    const float* tc = sT + lane * NODES_;
    u32 cp = 0;
    #pragma unroll
    for (int rr = 0; rr < 4; ++rr) {
        int node = 0, k = 0;
        #pragma unroll
        for (int l = 0; l < 4; ++l) {
            float h = vv[rr][l] - tc[node];
            int bit = (h > 0.0f) ? 1 : 0;
            k = (k << 1) | bit;
            node = (node << 1) + 1 + bit;
        }
        cp |= (u32)k << (4 * rr);
    }

    // ---- phase 2: thread = (row r of this wave's 4, cols q*8..q*8+7) ----
    const int r   = lane >> 4;   // 0..3
    const int q   = lane & 15;   // 0..15
    const int rsh = r * 4;

    float4 acc0 = make_float4(0.f, 0.f, 0.f, 0.f);
    float4 acc1 = make_float4(0.f, 0.f, 0.f, 0.f);

    #pragma unroll
    for (int p = 0; p < 32; ++p) {
        // wave-uniform broadcast of classes 2p, 2p+1 codes (constant lane idx)
        u32 ca = (u32)__builtin_amdgcn_readlane((int)cp, 2 * p);
        u32 cb = (u32)__builtin_amdgcn_readlane((int)cp, 2 * p + 1);
        u32 kk = ((ca >> rsh) & 15u) | (((cb >> rsh) & 15u) << 4);
        const uint4 v = *(const uint4*)(LUT + (((p << 8) | kk) << 7) + (q << 3));
        acc0.x += bf_lo(v.x); acc0.y += bf_hi(v.x);
        acc0.z += bf_lo(v.y); acc0.w += bf_hi(v.y);
        acc1.x += bf_lo(v.z); acc1.y += bf_hi(v.z);
        acc1.z += bf_lo(v.w); acc1.w += bf_hi(v.w);
    }

    float4* o = (float4*)(out + (size_t)(rowBase + r) * M_DIM + (q << 3));
    o[0] = acc0;
    o[1] = acc1;
}

extern "C" void kernel_launch(void* const* d_in, const int* in_sizes, int n_in,
                              void* d_out, int out_size, void* d_ws, size_t ws_size,
                              hipStream_t stream) {
    // inputs: I(0) T(1) L(2) S(3) B(4) dims(5) temp(6) — fp32, dims int32
    const float* I    = (const float*)d_in[0];
    const float* T    = (const float*)d_in[1];
    const float* L    = (const float*)d_in[2];
    const int*   dims = (const int*)d_in[5];

    u16* LUT = (u16*)d_ws;                                 // 2 MB scratch

    hipLaunchKernelGGL(build_lut_kernel, dim3(512), dim3(256), 0, stream, L, LUT);
    hipLaunchKernelGGL(fused_kernel, dim3(N_TOTAL / ROWS), dim3(256), 0, stream,
                       I, T, dims, LUT, (float*)d_out);
}

// Round 2
// 121.469 us; speedup vs baseline: 1.0408x; 1.0408x over previous
//
#include <hip/hip_runtime.h>

#define N_TOTAL 32768
#define D_DIM   512
#define C_DIM   64
#define K_DIM   16
#define M_DIM   128
#define NODES_  15
#define ROWS    16

typedef unsigned short u16;
typedef unsigned int   u32;

__device__ __forceinline__ u32 f2bf_bits(float f) {
    u32 u = __float_as_uint(f);
    return (u + 0x7FFFu + ((u >> 16) & 1u)) >> 16;   // RNE
}
__device__ __forceinline__ float bf_lo(u32 u) { return __uint_as_float(u << 16); }
__device__ __forceinline__ float bf_hi(u32 u) { return __uint_as_float(u & 0xFFFF0000u); }

// coalesced global -> LDS direct copy, 16 B/lane. LDS dest is wave-uniform
// base + lane*16 (HW-defined); global src is per-lane.
__device__ __forceinline__ void gload_lds16(const float* g, float* l) {
    __builtin_amdgcn_global_load_lds(
        (const __attribute__((address_space(1))) void*)g,
        (__attribute__((address_space(3))) void*)l, 16, 0, 0);
}

// ---------------------------------------------------------------------------
// Kernel 1: pair-merged LUT. LUT2[p][kk][m] (bf16), p=0..31, kk=k0|(k1<<4):
//   LUT2 = L[m][(2p)*16+k0] + L[m][(2p+1)*16+k1]
// 32*256*128 bf16 = 2 MB (L2/L3-resident). ~1-2 us, not the bottleneck.
// ---------------------------------------------------------------------------
__global__ __launch_bounds__(256) void build_lut_kernel(
    const float* __restrict__ L, u16* __restrict__ LUT)
{
    int idx = blockIdx.x * 256 + threadIdx.x;   // 131072 threads
    int q  = idx & 15;                          // col-group (8 cols)
    int kk = (idx >> 4) & 255;
    int p  = idx >> 12;                         // 0..31
    int c0 = (2 * p) * 16 + (kk & 15);
    int c1 = (2 * p + 1) * 16 + (kk >> 4);
    u32 w[4];
    #pragma unroll
    for (int h = 0; h < 4; ++h) {
        int m0 = q * 8 + 2 * h;
        float a0 = L[m0 * 1024 + c0]       + L[m0 * 1024 + c1];
        float a1 = L[(m0 + 1) * 1024 + c0] + L[(m0 + 1) * 1024 + c1];
        w[h] = f2bf_bits(a0) | (f2bf_bits(a1) << 16);
    }
    *(uint4*)(LUT + (size_t)((p << 8) | kk) * M_DIM + q * 8) =
        make_uint4(w[0], w[1], w[2], w[3]);
}

// ---------------------------------------------------------------------------
// Kernel 2 (fused): wave w owns rows blockIdx.x*16 + 4w .. +3.
// Phase 0: stage the wave's 4 rows (8 KB, contiguous) into LDS via
//          global_load_lds width=16 — 8 coalesced 1 KB instructions instead
//          of 16 scattered gathers (1024 addr-coalescer slots -> 8).
// Phase 1: depth-4 descent; the scatter (sorted-random dims) is now LDS
//          ds_read_b32 (per-lane scatter is native there, ~2 lanes/bank).
//          Codes packed 4x4b into one u32/lane (lane = class).
// Phase 2: readlane broadcasts -> 32 x 16 B L2 LUT loads/thread (unchanged,
//          verified in round 1).
// Forward of the STE reference: sign(h) drives a binary descent; argmax leaf
// == descent leaf. h==0 -> bit 0 == argmax first-max tie rule.
// ---------------------------------------------------------------------------
__global__ __launch_bounds__(256) void fused_kernel(
    const float* __restrict__ I,
    const float* __restrict__ T,
    const int* __restrict__ dims,
    const u16* __restrict__ LUT,
    float* __restrict__ out)
{
    __shared__ float sI[ROWS * D_DIM];      // 32 KB, wave w -> [4w*512 .. )
    __shared__ float sT[C_DIM * NODES_];    // 3.75 KB

    const int tid  = threadIdx.x;
    const int lane = tid & 63;              // class c in phase 1
    const int wv   = tid >> 6;              // wave 0..3
    const int rowBase = blockIdx.x * ROWS + wv * 4;

    // ---- phase 0: coalesced stage of this wave's 4 rows (issue first) ----
    {
        const float* src = I + (size_t)rowBase * D_DIM;   // 8 KB contiguous
        float* dst = sI + wv * 4 * D_DIM;
        #pragma unroll
        for (int i = 0; i < 8; ++i)
            gload_lds16(src + i * 256 + lane * 4, dst + i * 256);
    }

    // per-lane dim indices: one coalesced int4 (1 KB, L2-hot)
    const int4 dml = ((const int4*)dims)[lane];

    // stage thresholds while the LDS-stage is in flight
    for (int j = tid; j < C_DIM * NODES_; j += 256) sT[j] = T[j];
    __syncthreads();   // drains vmcnt -> sI and sT both ready

    // ---- phase 1: depth-4 descent, 4 rows, codes packed into one u32 ----
    const float* tc = sT + lane * NODES_;
    u32 cp = 0;
    #pragma unroll
    for (int rr = 0; rr < 4; ++rr) {
        const float* v = sI + (wv * 4 + rr) * D_DIM;
        float x0 = v[dml.x], x1 = v[dml.y], x2 = v[dml.z], x3 = v[dml.w];
        int node = 0, k = 0;
        float h0 = x0 - tc[0];
        int b0 = (h0 > 0.0f) ? 1 : 0;
        k = b0; node = 1 + b0;
        float h1 = x1 - tc[node];
        int b1 = (h1 > 0.0f) ? 1 : 0;
        k = (k << 1) | b1; node = (node << 1) + 1 + b1;
        float h2 = x2 - tc[node];
        int b2 = (h2 > 0.0f) ? 1 : 0;
        k = (k << 1) | b2; node = (node << 1) + 1 + b2;
        float h3 = x3 - tc[node];
        int b3 = (h3 > 0.0f) ? 1 : 0;
        k = (k << 1) | b3;
        cp |= (u32)k << (4 * rr);
    }

    // ---- phase 2: thread = (row r of this wave's 4, cols q*8..q*8+7) ----
    const int r   = lane >> 4;   // 0..3
    const int q   = lane & 15;   // 0..15
    const int rsh = r * 4;

    float4 acc0 = make_float4(0.f, 0.f, 0.f, 0.f);
    float4 acc1 = make_float4(0.f, 0.f, 0.f, 0.f);

    #pragma unroll
    for (int p = 0; p < 32; ++p) {
        // wave-uniform broadcast of classes 2p, 2p+1 codes (constant lane idx)
        u32 ca = (u32)__builtin_amdgcn_readlane((int)cp, 2 * p);
        u32 cb = (u32)__builtin_amdgcn_readlane((int)cp, 2 * p + 1);
        u32 kk = ((ca >> rsh) & 15u) | (((cb >> rsh) & 15u) << 4);
        const uint4 v = *(const uint4*)(LUT + (((p << 8) | kk) << 7) + (q << 3));
        acc0.x += bf_lo(v.x); acc0.y += bf_hi(v.x);
        acc0.z += bf_lo(v.y); acc0.w += bf_hi(v.y);
        acc1.x += bf_lo(v.z); acc1.y += bf_hi(v.z);
        acc1.z += bf_lo(v.w); acc1.w += bf_hi(v.w);
    }

    float4* o = (float4*)(out + (size_t)(rowBase + r) * M_DIM + (q << 3));
    o[0] = acc0;
    o[1] = acc1;
}

extern "C" void kernel_launch(void* const* d_in, const int* in_sizes, int n_in,
                              void* d_out, int out_size, void* d_ws, size_t ws_size,
                              hipStream_t stream) {
    // inputs: I(0) T(1) L(2) S(3) B(4) dims(5) temp(6) — fp32, dims int32
    const float* I    = (const float*)d_in[0];
    const float* T    = (const float*)d_in[1];
    const float* L    = (const float*)d_in[2];
    const int*   dims = (const int*)d_in[5];

    u16* LUT = (u16*)d_ws;                                 // 2 MB scratch

    hipLaunchKernelGGL(build_lut_kernel, dim3(512), dim3(256), 0, stream, L, LUT);
    hipLaunchKernelGGL(fused_kernel, dim3(N_TOTAL / ROWS), dim3(256), 0, stream,
                       I, T, dims, LUT, (float*)d_out);
}